// Round 1
// baseline (97.813 us; speedup 1.0000x reference)
//
#include <hip/hip_runtime.h>

// DarcyLoss: B=4096, C=2, H=W=64. Inputs (f32): model_out, target, x0_hat [B,2,64,64], var [B].
// Output: scalar f32 loss.
//
// loss = mean((mo-tg)^2) + mean_b( min(0.5*r_b^2/var_b, 27.6310211159) )
// r_b  = (sum(eq0) + sum(bc)) / (64*64*3);  source f_s sums to 0 -> omitted.

#define NB 4096
#define HW 4096          // 64*64
#define CHW 8192         // 2*64*64

__device__ __forceinline__ float fd1_lo(float f0, float f1, float f2, float s) {
    return (-3.0f * f0 + 4.0f * f1 - f2) * s;
}
__device__ __forceinline__ float fd1_hi(float fm1, float fm2, float fm3, float s) {
    return (3.0f * fm1 - 4.0f * fm2 + fm3) * s;
}

__global__ __launch_bounds__(256) void darcy_batch_kernel(
    const float* __restrict__ mo, const float* __restrict__ tg,
    const float* __restrict__ x0, const float* __restrict__ var,
    float* __restrict__ ws_res, float* __restrict__ ws_data)
{
    constexpr float INV2D = 31.5f;            // 1/(2*D), D = 1/63
    constexpr float INVD2 = 3969.0f;          // 1/D^2
    constexpr float CLAMP = 27.6310211159f;   // -CLAMP_MIN

    __shared__ __align__(16) float sp[64 * 64];   // p   = x0[:,0]
    __shared__ __align__(16) float sq[64 * 64];   // perm= x0[:,1]
    __shared__ float red[8];

    const int b = blockIdx.x;
    const int t = threadIdx.x;

    // ---- stage p and perm into LDS (float4, fully coalesced) ----
    const float4* p4 = (const float4*)(x0 + (size_t)b * CHW);
    const float4* q4 = (const float4*)(x0 + (size_t)b * CHW + HW);
    float4* sp4 = (float4*)sp;
    float4* sq4 = (float4*)sq;
    #pragma unroll
    for (int k = 0; k < 4; ++k) {
        sp4[t + k * 256] = p4[t + k * 256];
        sq4[t + k * 256] = q4[t + k * 256];
    }

    // ---- data-loss partial for this batch: sum (mo - tg)^2 over 2*64*64 ----
    const float4* m4 = (const float4*)(mo + (size_t)b * CHW);
    const float4* g4 = (const float4*)(tg + (size_t)b * CHW);
    float dsum = 0.0f;
    #pragma unroll
    for (int k = 0; k < 8; ++k) {
        float4 a = m4[t + k * 256];
        float4 c = g4[t + k * 256];
        float e0 = a.x - c.x, e1 = a.y - c.y, e2 = a.z - c.z, e3 = a.w - c.w;
        dsum += e0 * e0 + e1 * e1 + e2 * e2 + e3 * e3;
    }

    __syncthreads();

    // ---- residual sum: eq0 over all cells + boundary terms ----
    float rsum = 0.0f;
    #pragma unroll
    for (int k = 0; k < 16; ++k) {
        const int idx = t + k * 256;
        const int i = idx >> 6;
        const int j = idx & 63;
        const float* pr = sp + i * 64;
        const float* qr = sq + i * 64;

        // d/dW (axis -1) of p: first + second derivative
        float pd1, pd11;
        if (j == 0) {
            pd1  = fd1_lo(pr[0], pr[1], pr[2], INV2D);
            pd11 = (2.0f * pr[0] - 5.0f * pr[1] + 4.0f * pr[2] - pr[3]) * INVD2;
        } else if (j == 63) {
            pd1  = fd1_hi(pr[63], pr[62], pr[61], INV2D);
            pd11 = (2.0f * pr[63] - 5.0f * pr[62] + 4.0f * pr[61] - pr[60]) * INVD2;
        } else {
            pd1  = (pr[j + 1] - pr[j - 1]) * INV2D;
            pd11 = (pr[j + 1] - 2.0f * pr[j] + pr[j - 1]) * INVD2;
        }

        // d/dH (axis -2) of p (branches are wave-uniform: i is constant per 64-lane group)
        float pd0, pd00;
        if (i == 0) {
            pd0  = fd1_lo(sp[j], sp[64 + j], sp[128 + j], INV2D);
            pd00 = (2.0f * sp[j] - 5.0f * sp[64 + j] + 4.0f * sp[128 + j] - sp[192 + j]) * INVD2;
        } else if (i == 63) {
            pd0  = fd1_hi(sp[63 * 64 + j], sp[62 * 64 + j], sp[61 * 64 + j], INV2D);
            pd00 = (2.0f * sp[63 * 64 + j] - 5.0f * sp[62 * 64 + j] + 4.0f * sp[61 * 64 + j] - sp[60 * 64 + j]) * INVD2;
        } else {
            pd0  = (sp[(i + 1) * 64 + j] - sp[(i - 1) * 64 + j]) * INV2D;
            pd00 = (sp[(i + 1) * 64 + j] - 2.0f * sp[i * 64 + j] + sp[(i - 1) * 64 + j]) * INVD2;
        }

        // first derivatives of perm
        float qd1, qd0;
        if (j == 0)       qd1 = fd1_lo(qr[0], qr[1], qr[2], INV2D);
        else if (j == 63) qd1 = fd1_hi(qr[63], qr[62], qr[61], INV2D);
        else              qd1 = (qr[j + 1] - qr[j - 1]) * INV2D;
        if (i == 0)       qd0 = fd1_lo(sq[j], sq[64 + j], sq[128 + j], INV2D);
        else if (i == 63) qd0 = fd1_hi(sq[63 * 64 + j], sq[62 * 64 + j], sq[61 * 64 + j], INV2D);
        else              qd0 = (sq[(i + 1) * 64 + j] - sq[(i - 1) * 64 + j]) * INV2D;

        const float perm = qr[j];
        // eq0 = -perm*p_d00 - perm_d0*p_d0 - perm*p_d11 - perm_d1*p_d1  (f_s omitted: sums to 0)
        rsum += -perm * (pd00 + pd11) - qd0 * pd0 - qd1 * pd1;

        // boundary-condition contributions to the residual sum
        if (i == 0)  rsum -= pd0;
        if (i == 63) rsum += pd0;
        if (j == 0)  rsum += pd1;
        if (j == 63) rsum -= pd1;
    }

    // ---- block reduction (wave64 shuffle, then LDS across 4 waves) ----
    #pragma unroll
    for (int off = 32; off > 0; off >>= 1) {
        rsum += __shfl_down(rsum, off);
        dsum += __shfl_down(dsum, off);
    }
    const int wid = t >> 6, lane = t & 63;
    if (lane == 0) { red[wid] = rsum; red[4 + wid] = dsum; }
    __syncthreads();
    if (t == 0) {
        const float rs = red[0] + red[1] + red[2] + red[3];
        const float ds = red[4] + red[5] + red[6] + red[7];
        const float r  = rs * (1.0f / (64.0f * 64.0f * 3.0f));
        const float v  = var[b];
        float res = 0.5f * r * r / v;
        res = fminf(res, CLAMP);
        ws_res[b]  = res;
        ws_data[b] = ds;
    }
}

__global__ __launch_bounds__(256) void darcy_final_kernel(
    const float* __restrict__ ws_res, const float* __restrict__ ws_data,
    float* __restrict__ out)
{
    const int t = threadIdx.x;
    double rs = 0.0, ds = 0.0;
    for (int i = t; i < NB; i += 256) {
        rs += (double)ws_res[i];
        ds += (double)ws_data[i];
    }
    #pragma unroll
    for (int off = 32; off > 0; off >>= 1) {
        rs += __shfl_down(rs, off);
        ds += __shfl_down(ds, off);
    }
    __shared__ double red[8];
    const int wid = t >> 6, lane = t & 63;
    if (lane == 0) { red[wid] = rs; red[4 + wid] = ds; }
    __syncthreads();
    if (t == 0) {
        const double R = red[0] + red[1] + red[2] + red[3];
        const double Dd = red[4] + red[5] + red[6] + red[7];
        out[0] = (float)(Dd / ((double)NB * (double)CHW) + R / (double)NB);
    }
}

extern "C" void kernel_launch(void* const* d_in, const int* in_sizes, int n_in,
                              void* d_out, int out_size, void* d_ws, size_t ws_size,
                              hipStream_t stream) {
    const float* mo  = (const float*)d_in[0];
    const float* tg  = (const float*)d_in[1];
    const float* x0  = (const float*)d_in[2];
    const float* var = (const float*)d_in[3];
    float* out = (float*)d_out;

    float* ws_res  = (float*)d_ws;          // NB floats
    float* ws_data = ws_res + NB;           // NB floats

    darcy_batch_kernel<<<NB, 256, 0, stream>>>(mo, tg, x0, var, ws_res, ws_data);
    darcy_final_kernel<<<1, 256, 0, stream>>>(ws_res, ws_data, out);
}

// Round 2
// 84.898 us; speedup vs baseline: 1.1521x; 1.1521x over previous
//
#include <hip/hip_runtime.h>

// DarcyLoss: B=4096, C=2, H=W=64. Inputs (f32): model_out, target, x0_hat [B,2,64,64], var [B].
// Output: scalar f32 loss = mean((mo-tg)^2) + mean_b( min(0.5*r_b^2/var_b, 27.6310211159) )
// r_b = (sum(eq0) + sum(bc)) / (64*64*3);  source f_s sums to 0 -> omitted.
//
// Structure: one WAVE per batch. Lane j owns column j. Vertical stencils via a
// rolling register window (prefetch 2 rows ahead); horizontal stencils via __shfl.
// No LDS, no __syncthreads -> occupancy limited only by VGPRs; every wave
// independently overlaps loads and compute.

#define NB 4096
#define HW 4096          // 64*64
#define CHW 8192         // 2*64*64

__device__ __forceinline__ void hderiv2(float v, int j, float& d1, float& d11) {
    constexpr float INV2D = 31.5f, INVD2 = 3969.0f;
    float vm = __shfl(v, (j + 63) & 63);   // j-1 (unused at j=0)
    float vp = __shfl(v, (j + 1) & 63);    // j+1 (unused at j=63)
    float v2 = __shfl(v, (j == 0) ? 2 : 61);
    float v3 = __shfl(v, (j == 0) ? 3 : 60);
    d1  = (vp - vm) * INV2D;
    d11 = (vp - 2.0f * v + vm) * INVD2;
    if (j == 0)  { d1 = (-3.0f * v + 4.0f * vp - v2) * INV2D;
                   d11 = (2.0f * v - 5.0f * vp + 4.0f * v2 - v3) * INVD2; }
    if (j == 63) { d1 = ( 3.0f * v - 4.0f * vm + v2) * INV2D;
                   d11 = (2.0f * v - 5.0f * vm + 4.0f * v2 - v3) * INVD2; }
}

__device__ __forceinline__ float hderiv1(float v, int j) {
    constexpr float INV2D = 31.5f;
    float vm = __shfl(v, (j + 63) & 63);
    float vp = __shfl(v, (j + 1) & 63);
    float v2 = __shfl(v, (j == 0) ? 2 : 61);
    float d = (vp - vm) * INV2D;
    if (j == 0)  d = (-3.0f * v + 4.0f * vp - v2) * INV2D;
    if (j == 63) d = ( 3.0f * v - 4.0f * vm + v2) * INV2D;
    return d;
}

__global__ __launch_bounds__(256, 8) void darcy_wave_kernel(
    const float* __restrict__ mo, const float* __restrict__ tg,
    const float* __restrict__ x0, const float* __restrict__ var,
    float* __restrict__ ws_res, float* __restrict__ ws_data)
{
    constexpr float INV2D = 31.5f;
    constexpr float INVD2 = 3969.0f;
    constexpr float CLAMP = 27.6310211159f;

    const int wave = threadIdx.x >> 6;
    const int j    = threadIdx.x & 63;
    const int b    = blockIdx.x * 4 + wave;

    const float*  pb = x0 + (size_t)b * CHW;        // p    plane
    const float*  qb = pb + HW;                     // perm plane
    const float4* m4 = (const float4*)(mo + (size_t)b * CHW);
    const float4* g4 = (const float4*)(tg + (size_t)b * CHW);

    float rsum = 0.0f, dsum = 0.0f;

    // ---- preload rows 0..3 ----
    float pm = pb[j], pc = pb[64 + j], pp = pb[128 + j], pn = pb[192 + j];
    float qm = qb[j], qc = qb[64 + j], qp = qb[128 + j], qn = qb[192 + j];

    // ---- row i = 0 (one-sided vertical) ----
    {
        float pd1, pd11;
        hderiv2(pm, j, pd1, pd11);
        float qd1 = hderiv1(qm, j);
        float pd0  = (-3.0f * pm + 4.0f * pc - pp) * INV2D;
        float pd00 = (2.0f * pm - 5.0f * pc + 4.0f * pp - pn) * INVD2;
        float qd0  = (-3.0f * qm + 4.0f * qc - qp) * INV2D;
        rsum += -qm * (pd00 + pd11) - qd0 * pd0 - qd1 * pd1 - pd0;   // bc(i=0): -pd0
        rsum += (j == 0) ? pd1 : 0.0f;
        rsum -= (j == 63) ? pd1 : 0.0f;
    }

    float s_p60 = 0.0f, s_p61 = 0.0f, s_q61 = 0.0f;

    // ---- rows i = 1..62 (central vertical); fused mo/tg streaming in i<=32 ----
    #pragma unroll 2
    for (int i = 1; i <= 62; ++i) {
        // prefetch row i+3 (used as pn two iterations later)
        float pn2 = 0.0f, qn2 = 0.0f;
        if (i <= 60) {
            pn2 = pb[((i + 3) << 6) + j];
            qn2 = qb[((i + 3) << 6) + j];
        }
        // fused data-loss streaming: chunk i-1 of 32
        if (i <= 32) {
            const int k = (i - 1) << 6;
            float4 a = m4[j + k];
            float4 c = g4[j + k];
            float e0 = a.x - c.x, e1 = a.y - c.y, e2 = a.z - c.z, e3 = a.w - c.w;
            dsum += e0 * e0 + e1 * e1 + e2 * e2 + e3 * e3;
        }

        float pd1, pd11;
        hderiv2(pc, j, pd1, pd11);
        float qd1 = hderiv1(qc, j);
        float pd0  = (pp - pm) * INV2D;
        float pd00 = (pp - 2.0f * pc + pm) * INVD2;
        float qd0  = (qp - qm) * INV2D;
        rsum += -qc * (pd00 + pd11) - qd0 * pd0 - qd1 * pd1;
        rsum += (j == 0) ? pd1 : 0.0f;
        rsum -= (j == 63) ? pd1 : 0.0f;

        if (i == 61) s_p60 = pm;                 // pm = p[60]
        if (i == 62) { s_p61 = pm; s_q61 = qm; } // pm = p[61], qm = q[61]

        // rotate windows
        pm = pc; pc = pp; pp = pn; pn = pn2;
        qm = qc; qc = qp; qp = qn; qn = qn2;
    }

    // ---- row i = 63 (one-sided vertical); window: pm=p62, pc=p63 ----
    {
        float pd1, pd11;
        hderiv2(pc, j, pd1, pd11);
        float qd1 = hderiv1(qc, j);
        float pd0  = (3.0f * pc - 4.0f * pm + s_p61) * INV2D;
        float pd00 = (2.0f * pc - 5.0f * pm + 4.0f * s_p61 - s_p60) * INVD2;
        float qd0  = (3.0f * qc - 4.0f * qm + s_q61) * INV2D;
        rsum += -qc * (pd00 + pd11) - qd0 * pd0 - qd1 * pd1 + pd0;   // bc(i=63): +pd0
        rsum += (j == 0) ? pd1 : 0.0f;
        rsum -= (j == 63) ? pd1 : 0.0f;
    }

    // ---- per-wave reduction (wave == batch, no cross-wave needed) ----
    #pragma unroll
    for (int off = 32; off > 0; off >>= 1) {
        rsum += __shfl_down(rsum, off);
        dsum += __shfl_down(dsum, off);
    }
    if (j == 0) {
        const float r = rsum * (1.0f / (64.0f * 64.0f * 3.0f));
        float res = 0.5f * r * r / var[b];
        ws_res[b]  = fminf(res, CLAMP);
        ws_data[b] = dsum;
    }
}

__global__ __launch_bounds__(256) void darcy_final_kernel(
    const float* __restrict__ ws_res, const float* __restrict__ ws_data,
    float* __restrict__ out)
{
    const int t = threadIdx.x;
    double rs = 0.0, ds = 0.0;
    for (int i = t; i < NB; i += 256) {
        rs += (double)ws_res[i];
        ds += (double)ws_data[i];
    }
    #pragma unroll
    for (int off = 32; off > 0; off >>= 1) {
        rs += __shfl_down(rs, off);
        ds += __shfl_down(ds, off);
    }
    __shared__ double red[8];
    const int wid = t >> 6, lane = t & 63;
    if (lane == 0) { red[wid] = rs; red[4 + wid] = ds; }
    __syncthreads();
    if (t == 0) {
        const double R  = red[0] + red[1] + red[2] + red[3];
        const double Dd = red[4] + red[5] + red[6] + red[7];
        out[0] = (float)(Dd / ((double)NB * (double)CHW) + R / (double)NB);
    }
}

extern "C" void kernel_launch(void* const* d_in, const int* in_sizes, int n_in,
                              void* d_out, int out_size, void* d_ws, size_t ws_size,
                              hipStream_t stream) {
    const float* mo  = (const float*)d_in[0];
    const float* tg  = (const float*)d_in[1];
    const float* x0  = (const float*)d_in[2];
    const float* var = (const float*)d_in[3];
    float* out = (float*)d_out;

    float* ws_res  = (float*)d_ws;          // NB floats
    float* ws_data = ws_res + NB;           // NB floats

    darcy_wave_kernel<<<NB / 4, 256, 0, stream>>>(mo, tg, x0, var, ws_res, ws_data);
    darcy_final_kernel<<<1, 256, 0, stream>>>(ws_res, ws_data, out);
}